// Round 2
// baseline (1596.333 us; speedup 1.0000x reference)
//
#include <hip/hip_runtime.h>
#include <hip/hip_bf16.h>
#include <float.h>

// Performer FastAttention (FAVOR+), fp32 SIMT baseline (round 2: fix ctx split bug).
// q,k,v: [8,12,4096,64] f32; proj: [256,64] f32; out: [8,12,4096,64] f32.

namespace {
constexpr int Bc = 8, Hc = 12, Nn = 4096, Dd = 64, Mm = 256;
constexpr int BH = Bc * Hc;
constexpr float kNormalizer = 0.35355339059327379f;  // 64^-0.25
constexpr float kRatio      = 0.0625f;               // 256^-0.5
constexpr float kDiagCoef   = 0.0625f;               // 0.5 * 64^-0.5
constexpr float kEps        = 1e-4f;

// workspace layout (bytes)
constexpr size_t kOffKsum = 4096;                                  // BH*256 f32
constexpr size_t kOffCtx  = kOffKsum + (size_t)BH * Mm * 4;        // BH*64*256 f32, layout [bh][e][m]
constexpr size_t kWsBytes = kOffCtx + (size_t)BH * Dd * Mm * 4;    // ~6.1 MB
}

static __device__ __forceinline__ unsigned floatKey(float f) {
  unsigned b = __float_as_uint(f);
  return (b & 0x80000000u) ? ~b : (b | 0x80000000u);
}
static __device__ __forceinline__ float keyToFloat(unsigned k) {
  unsigned b = (k & 0x80000000u) ? (k & 0x7fffffffu) : ~k;
  return __uint_as_float(b);
}

#define LOAD_PROJ_ROW(pr, proj, m)                                         \
  {                                                                        \
    const float4* pj_ = reinterpret_cast<const float4*>(proj) + (m) * 16;  \
    _Pragma("unroll") for (int i_ = 0; i_ < 16; ++i_) {                    \
      float4 w_ = pj_[i_];                                                 \
      pr[4 * i_ + 0] = w_.x; pr[4 * i_ + 1] = w_.y;                        \
      pr[4 * i_ + 2] = w_.z; pr[4 * i_ + 3] = w_.w;                        \
    }                                                                      \
  }

// ---------------------------------------------------------------------------
// Kernel 1: per-head global max of dd_k = normalizer * (k . proj^T)
// grid (BH, 8), block 512. 512 rows/block; thread t owns m = t&255.
// ---------------------------------------------------------------------------
__global__ __launch_bounds__(512) void perf_kmax(const float* __restrict__ K,
                                                 const float* __restrict__ proj,
                                                 unsigned* __restrict__ stabKey) {
  const int t = threadIdx.x;
  const int bh = blockIdx.x;
  const int chunk = blockIdx.y;
  const int m = t & 255;
  const int half = t >> 8;

  float pr[64];
  LOAD_PROJ_ROW(pr, proj, m);

  __shared__ float kt[64][64];
  __shared__ float wmax[8];

  float mx = -FLT_MAX;
  const float* kbase = K + ((size_t)bh * Nn + (size_t)chunk * 512) * Dd;
  for (int sub = 0; sub < 8; ++sub) {
    __syncthreads();
    const float4* src = reinterpret_cast<const float4*>(kbase + sub * 64 * Dd);
    float4* dst = reinterpret_cast<float4*>(&kt[0][0]);
#pragma unroll
    for (int i = 0; i < 2; ++i) dst[t + 512 * i] = src[t + 512 * i];
    __syncthreads();
#pragma unroll 2
    for (int rr = 0; rr < 32; ++rr) {
      const int r = half * 32 + rr;
      const float4* krow = reinterpret_cast<const float4*>(&kt[r][0]);
      float acc = 0.f;
#pragma unroll
      for (int i = 0; i < 16; ++i) {
        float4 kv = krow[i];
        acc = fmaf(kv.x, pr[4 * i + 0], acc);
        acc = fmaf(kv.y, pr[4 * i + 1], acc);
        acc = fmaf(kv.z, pr[4 * i + 2], acc);
        acc = fmaf(kv.w, pr[4 * i + 3], acc);
      }
      mx = fmaxf(mx, acc);
    }
  }
  mx *= kNormalizer;
#pragma unroll
  for (int off = 32; off > 0; off >>= 1) mx = fmaxf(mx, __shfl_xor(mx, off, 64));
  if ((t & 63) == 0) wmax[t >> 6] = mx;
  __syncthreads();
  if (t == 0) {
    float b = wmax[0];
#pragma unroll
    for (int w = 1; w < 8; ++w) b = fmaxf(b, wmax[w]);
    atomicMax(stabKey + bh, floatKey(b));
  }
}

// ---------------------------------------------------------------------------
// Kernel 2: k' = ratio*(exp(dd - diag - stab)+eps); accumulate
//   ksum[m] += sum_n k'[n,m];  ctx[e][m] += sum_n k'[n,m]*v[n,e]
// grid (BH, 16), block 512. 256 rows/block.
// Thread t: m = t&255, half = t>>8. Computes kp for rows half*32..+31 into
// kp_sh, then accumulates e-slice half*32..+31 over ALL 64 rows (fixes the
// round-1 bug where cross-half (row, e) contributions were dropped).
// ---------------------------------------------------------------------------
__global__ __launch_bounds__(512) void perf_kctx(const float* __restrict__ K,
                                                 const float* __restrict__ V,
                                                 const float* __restrict__ proj,
                                                 const unsigned* __restrict__ stabKey,
                                                 float* __restrict__ ksum,
                                                 float* __restrict__ ctx) {
  const int t = threadIdx.x;
  const int bh = blockIdx.x;
  const int chunk = blockIdx.y;
  const int m = t & 255;
  const int half = t >> 8;

  float pr[64];
  LOAD_PROJ_ROW(pr, proj, m);
  const float stab = keyToFloat(stabKey[bh]);

  __shared__ float kt[64][64];
  __shared__ float vt[64][64];
  __shared__ float kp_sh[64][256];
  __shared__ float diag[64];

  float cacc[32];
#pragma unroll
  for (int j = 0; j < 32; ++j) cacc[j] = 0.f;
  float ksl = 0.f;

  const size_t base = ((size_t)bh * Nn + (size_t)chunk * 256) * Dd;
  for (int sub = 0; sub < 4; ++sub) {
    __syncthreads();
    const float4* ks = reinterpret_cast<const float4*>(K + base + sub * 64 * Dd);
    const float4* vs = reinterpret_cast<const float4*>(V + base + sub * 64 * Dd);
    float4* kd = reinterpret_cast<float4*>(&kt[0][0]);
    float4* vd = reinterpret_cast<float4*>(&vt[0][0]);
#pragma unroll
    for (int i = 0; i < 2; ++i) {
      kd[t + 512 * i] = ks[t + 512 * i];
      vd[t + 512 * i] = vs[t + 512 * i];
    }
    __syncthreads();
    if (t < 64) {
      float s = 0.f;
#pragma unroll
      for (int d = 0; d < 64; ++d) { float x = kt[t][d]; s = fmaf(x, x, s); }
      diag[t] = s * kDiagCoef;
    }
    __syncthreads();
    // kp for this thread's 32 rows -> kp_sh
#pragma unroll 2
    for (int rr = 0; rr < 32; ++rr) {
      const int r = half * 32 + rr;
      const float4* krow = reinterpret_cast<const float4*>(&kt[r][0]);
      float acc = 0.f;
#pragma unroll
      for (int i = 0; i < 16; ++i) {
        float4 kv = krow[i];
        acc = fmaf(kv.x, pr[4 * i + 0], acc);
        acc = fmaf(kv.y, pr[4 * i + 1], acc);
        acc = fmaf(kv.z, pr[4 * i + 2], acc);
        acc = fmaf(kv.w, pr[4 * i + 3], acc);
      }
      const float dd = kNormalizer * acc;
      const float kp = kRatio * (__expf(dd - diag[r] - stab) + kEps);
      ksl += kp;
      kp_sh[r][m] = kp;
    }
    __syncthreads();
    // accumulate e-slice over ALL 64 rows
#pragma unroll 4
    for (int r = 0; r < 64; ++r) {
      const float kp = kp_sh[r][m];
      const float4* vrow = reinterpret_cast<const float4*>(&vt[r][half * 32]);
#pragma unroll
      for (int i = 0; i < 8; ++i) {
        float4 vv = vrow[i];
        cacc[4 * i + 0] = fmaf(kp, vv.x, cacc[4 * i + 0]);
        cacc[4 * i + 1] = fmaf(kp, vv.y, cacc[4 * i + 1]);
        cacc[4 * i + 2] = fmaf(kp, vv.z, cacc[4 * i + 2]);
        cacc[4 * i + 3] = fmaf(kp, vv.w, cacc[4 * i + 3]);
      }
    }
  }
  atomicAdd(&ksum[(size_t)bh * Mm + m], ksl);
  float* cb = ctx + ((size_t)bh * Dd + half * 32) * Mm + m;
#pragma unroll
  for (int j = 0; j < 32; ++j) atomicAdd(cb + (size_t)j * Mm, cacc[j]);
}

// ---------------------------------------------------------------------------
// Kernel 3: q' + denom + output GEMM.  grid (BH, 64), block 512, 64 rows/blk.
// LDS: qt 16K + qp[64][260] 65K + CL[64][260] 65K + small = ~150K (1 blk/CU).
// ---------------------------------------------------------------------------
__global__ __launch_bounds__(512) void perf_out(const float* __restrict__ Q,
                                                const float* __restrict__ proj,
                                                const float* __restrict__ ksumg,
                                                const float* __restrict__ ctx,
                                                float* __restrict__ out) {
  const int t = threadIdx.x;
  const int bh = blockIdx.x;
  const int rb = blockIdx.y;
  const int m = t & 255;
  const int half = t >> 8;
  const int tx = t & 15;
  const int ty = (t >> 4) & 31;

  float pr[64];
  LOAD_PROJ_ROW(pr, proj, m);

  __shared__ float qt[64][64];
  __shared__ float qp[64][260];   // stride 260: 16B-aligned rows, bank offset 4
  __shared__ float CL[64][260];   // CL[e][m]
  __shared__ float ksl[256];
  __shared__ float diagl[64];
  __shared__ float shiftl[64];
  __shared__ float denl[64];
  __shared__ float rpart[64][8];

  {  // load q tile
    const float4* src = reinterpret_cast<const float4*>(Q + ((size_t)bh * Nn + (size_t)rb * 64) * Dd);
    float4* dst = reinterpret_cast<float4*>(&qt[0][0]);
#pragma unroll
    for (int i = 0; i < 2; ++i) dst[t + 512 * i] = src[t + 512 * i];
  }
  {  // load context [bh][e][m] -> CL[e][m]
    const float4* src = reinterpret_cast<const float4*>(ctx + (size_t)bh * Dd * Mm);
#pragma unroll
    for (int i = 0; i < 8; ++i) {
      int idx = t + 512 * i;
      int e = idx >> 6;
      int mq = idx & 63;
      *reinterpret_cast<float4*>(&CL[e][mq * 4]) = src[idx];
    }
  }
  if (t < 64) {
    const float4* src = reinterpret_cast<const float4*>(ksumg + (size_t)bh * Mm);
    *reinterpret_cast<float4*>(&ksl[t * 4]) = src[t];
  }
  __syncthreads();

  if (t < 64) {
    float s = 0.f;
#pragma unroll
    for (int d = 0; d < 64; ++d) { float x = qt[t][d]; s = fmaf(x, x, s); }
    diagl[t] = s * kDiagCoef;
  }
  // dd pass: thread computes dd for (its 32 rows, m)
#pragma unroll 2
  for (int rr = 0; rr < 32; ++rr) {
    const int r = half * 32 + rr;
    const float4* qrow = reinterpret_cast<const float4*>(&qt[r][0]);
    float acc = 0.f;
#pragma unroll
    for (int i = 0; i < 16; ++i) {
      float4 qv = qrow[i];
      acc = fmaf(qv.x, pr[4 * i + 0], acc);
      acc = fmaf(qv.y, pr[4 * i + 1], acc);
      acc = fmaf(qv.z, pr[4 * i + 2], acc);
      acc = fmaf(qv.w, pr[4 * i + 3], acc);
    }
    qp[r][m] = kNormalizer * acc;
  }
  __syncthreads();

  {  // row-max partials: 8 threads per row
    const int r = t & 63;
    const int oct = t >> 6;
    float lm = -FLT_MAX;
#pragma unroll
    for (int i = 0; i < 32; ++i) lm = fmaxf(lm, qp[r][oct * 32 + i]);
    rpart[r][oct] = lm;
  }
  __syncthreads();
  if (t < 64) {
    float rm = rpart[t][0];
#pragma unroll
    for (int o = 1; o < 8; ++o) rm = fmaxf(rm, rpart[t][o]);
    shiftl[t] = diagl[t] + rm;
  }
  __syncthreads();

  // exp pass -> q'
#pragma unroll 4
  for (int i = 0; i < 32; ++i) {
    const int r = half * 32 + i;
    float v = qp[r][m];
    qp[r][m] = kRatio * (__expf(v - shiftl[r]) + kEps);
  }
  __syncthreads();

  {  // denominator partials
    const int r = t & 63;
    const int oct = t >> 6;
    float p = 0.f;
#pragma unroll
    for (int i = 0; i < 32; ++i) p = fmaf(qp[r][oct * 32 + i], ksl[oct * 32 + i], p);
    rpart[r][oct] = p;
  }
  __syncthreads();
  if (t < 64) {
    float s = rpart[t][0];
#pragma unroll
    for (int o = 1; o < 8; ++o) s += rpart[t][o];
    denl[t] = 1.f / s;
  }
  __syncthreads();

  // output GEMM: out[r][e] = sum_m q'[r][m] * CL[e][m]
  float acc[2][4];
#pragma unroll
  for (int i = 0; i < 2; ++i)
#pragma unroll
    for (int j = 0; j < 4; ++j) acc[i][j] = 0.f;

#pragma unroll 4
  for (int mm = 0; mm < 256; mm += 4) {
    const float4 qv0 = *reinterpret_cast<const float4*>(&qp[ty][mm]);
    const float4 qv1 = *reinterpret_cast<const float4*>(&qp[ty + 32][mm]);
#pragma unroll
    for (int j = 0; j < 4; ++j) {
      const float4 cv = *reinterpret_cast<const float4*>(&CL[tx + 16 * j][mm]);
      acc[0][j] = fmaf(qv0.x, cv.x, acc[0][j]);
      acc[0][j] = fmaf(qv0.y, cv.y, acc[0][j]);
      acc[0][j] = fmaf(qv0.z, cv.z, acc[0][j]);
      acc[0][j] = fmaf(qv0.w, cv.w, acc[0][j]);
      acc[1][j] = fmaf(qv1.x, cv.x, acc[1][j]);
      acc[1][j] = fmaf(qv1.y, cv.y, acc[1][j]);
      acc[1][j] = fmaf(qv1.z, cv.z, acc[1][j]);
      acc[1][j] = fmaf(qv1.w, cv.w, acc[1][j]);
    }
  }

  float* obase = out + ((size_t)bh * Nn + (size_t)rb * 64) * Dd;
#pragma unroll
  for (int i = 0; i < 2; ++i) {
    const int r = ty + 32 * i;
    const float di = denl[r];
#pragma unroll
    for (int j = 0; j < 4; ++j) {
      obase[(size_t)r * Dd + tx + 16 * j] = acc[i][j] * di;
    }
  }
}

extern "C" void kernel_launch(void* const* d_in, const int* in_sizes, int n_in,
                              void* d_out, int out_size, void* d_ws, size_t ws_size,
                              hipStream_t stream) {
  const float* q = (const float*)d_in[0];
  const float* k = (const float*)d_in[1];
  const float* v = (const float*)d_in[2];
  const float* proj = (const float*)d_in[3];
  float* out = (float*)d_out;

  unsigned* stabKey = (unsigned*)d_ws;                      // 96 keys; 0 == key(-huge)
  float* ksum = (float*)((char*)d_ws + kOffKsum);
  float* ctx  = (float*)((char*)d_ws + kOffCtx);

  hipMemsetAsync(d_ws, 0, kWsBytes, stream);
  perf_kmax<<<dim3(BH, 8), 512, 0, stream>>>(k, proj, stabKey);
  perf_kctx<<<dim3(BH, 16), 512, 0, stream>>>(k, v, proj, stabKey, ksum, ctx);
  perf_out<<<dim3(BH, 64), 512, 0, stream>>>(q, proj, ksum, ctx, out);
}

// Round 3
// 430.452 us; speedup vs baseline: 3.7085x; 3.7085x over previous
//
#include <hip/hip_runtime.h>
#include <float.h>

// Performer FastAttention (FAVOR+), MFMA bf16-split implementation.
// q,k,v: [8,12,4096,64] f32; proj: [256,64] f32; out: [8,12,4096,64] f32.
//
// Math: k' = ratio*(exp(ddk - diagk - stab)+eps), stab = per-head max(ddk).
//   Factor exp(-stab): accumulate E = exp(ddk - diagk) (safe in fp32),
//   ctxE[m][e] = sum_n E*v, Esum[m] = sum_n E, Vsum[e] = sum_n v, stab = max dd.
//   ctxhat = e^{-stab}*ctxE + eps*Vsum ; kshat = e^{-stab}*Esum + eps*4096.
//   out[r][e] = (sum_m q'[r][m]*ctxhat[m][e]) / (sum_m q'[r][m]*kshat[m]),
//   q'   = exp(ddq - diagq - rowmax) + eps   (all ratio factors cancel).
// All GEMMs: mfma_f32_16x16x32_bf16 with 3-term hi/lo split (rel err ~2^-17).

typedef __attribute__((ext_vector_type(8))) short short8v;
typedef __attribute__((ext_vector_type(4))) short short4v;
typedef __attribute__((ext_vector_type(4))) float f32x4;

#define MFMA16(a, b, c) __builtin_amdgcn_mfma_f32_16x16x32_bf16(a, b, c, 0, 0, 0)

namespace {
constexpr int Nn = 4096, Dd = 64, Mm = 256, BHn = 96;
constexpr float kNorm = 0.35355339059327379f;  // 64^-0.25
constexpr float kDiagCoef = 0.0625f;           // 0.5 * 64^-0.5
constexpr float kEps = 1e-4f;

// workspace layout (bytes)
constexpr size_t oStab  = 0;                                  // 96 u32
constexpr size_t oEsum  = 512;                                // 96*256 f32
constexpr size_t oVsum  = oEsum + (size_t)BHn * 256 * 4;      // 96*64 f32
constexpr size_t oKshat = oVsum + (size_t)BHn * 64 * 4;       // 96*256 f32
constexpr size_t oCtxE  = oKshat + (size_t)BHn * 256 * 4;     // 96*256*64 f32
constexpr size_t oCtH   = oCtxE + (size_t)BHn * 256 * 64 * 4; // 96*64*256 s16
constexpr size_t oCtL   = oCtH + (size_t)BHn * 64 * 256 * 2;
constexpr size_t kZeroBytes = oCtH;  // zero stab..ctxE
}

static __device__ __forceinline__ unsigned floatKey(float f) {
  unsigned b = __float_as_uint(f);
  return (b & 0x80000000u) ? ~b : (b | 0x80000000u);
}
static __device__ __forceinline__ float keyToFloat(unsigned k) {
  unsigned b = (k & 0x80000000u) ? (k & 0x7fffffffu) : ~k;
  return __uint_as_float(b);
}
static __device__ __forceinline__ short bf16rne(float x) {
  unsigned b = __float_as_uint(x);
  unsigned r = (b + 0x7fffu + ((b >> 16) & 1u)) >> 16;
  return (short)r;
}
static __device__ __forceinline__ float bf16tof(short s) {
  return __uint_as_float(((unsigned)(unsigned short)s) << 16);
}
static __device__ __forceinline__ void splitbf(float x, short& h, short& l) {
  h = bf16rne(x);
  l = bf16rne(x - bf16tof(h));
}
// LDS block swizzles (element-index XOR; rows of 64 elems = 8 16B-blocks,
// rows of 128 elems = 16 blocks, rows of 256 elems = 32 blocks)
static __device__ __forceinline__ int sw8(int row, int col)  { return col ^ ((row & 7) << 3); }
static __device__ __forceinline__ int sw16(int row, int col) { return col ^ ((row & 15) << 3); }
static __device__ __forceinline__ int sw32(int row, int col) { return col ^ ((row & 31) << 3); }

// ---------------------------------------------------------------------------
// Kernel A: K-side. grid (96, 16), block 512 (8 waves). 256 rows/block.
// Per 64-row subtile: dd = (norm*k)·proj^T (split MFMA), E = exp(dd-diag),
// ctxE += E^T·v (split MFMA), Esum += E, Vsum += v, stab = max dd.
// ---------------------------------------------------------------------------
__global__ __launch_bounds__(512, 1) void perf_kside(
    const float* __restrict__ K, const float* __restrict__ V,
    const float* __restrict__ proj, unsigned* __restrict__ stabKey,
    float* __restrict__ EsumG, float* __restrict__ VsumG,
    float* __restrict__ ctxEG) {
  const int t = threadIdx.x;
  const int bh = blockIdx.x, chunk = blockIdx.y;
  const int w = t >> 6, l = t & 63;

  __shared__ short Kh[64][64], Kl[64][64];
  __shared__ short Vh[64][64], Vl[64][64];   // transposed: [e][n]
  __shared__ float vtmp[64][68];
  __shared__ short Ph[256][64], Pl[256][64];
  __shared__ short Eh[128][64], El[128][64]; // transposed: [m_half][n]
  __shared__ float diag[64];
  __shared__ float rpartV[8][64];
  __shared__ float wpmax[8];

  // stage proj once (both halves)
  {
    const int m = t >> 1, d0 = (t & 1) * 32;
    const float* src = proj + m * 64 + d0;
#pragma unroll
    for (int i = 0; i < 4; ++i) {
      float4 a = *(const float4*)(src + i * 8);
      float4 b = *(const float4*)(src + i * 8 + 4);
      float xs[8] = {a.x, a.y, a.z, a.w, b.x, b.y, b.z, b.w};
      short8v h8, l8;
#pragma unroll
      for (int j = 0; j < 8; ++j) { short hh, ll; splitbf(xs[j], hh, ll); h8[j] = hh; l8[j] = ll; }
      const int c = sw8(m, d0 + i * 8);
      *(short8v*)&Ph[m][c] = h8;
      *(short8v*)&Pl[m][c] = l8;
    }
  }

  const int rt = w & 3, msel = w >> 2;
  const int koff = (l >> 4) * 8;
  float mx = -FLT_MAX;
  float vsum_r = 0.f;
  f32x4 cacc[2][4];
  float es[2][4];
#pragma unroll
  for (int a = 0; a < 2; ++a)
#pragma unroll
    for (int b = 0; b < 4; ++b) { cacc[a][b] = f32x4{0.f, 0.f, 0.f, 0.f}; es[a][b] = 0.f; }

  const size_t headBase = ((size_t)bh * Nn + chunk * 256) * Dd;

  for (int sub = 0; sub < 4; ++sub) {
    __syncthreads();
    {  // stage K (+diag) and V->vtmp
      const int n = t >> 3, d0 = (t & 7) * 8;
      const float* ks = K + headBase + (size_t)(sub * 64 + n) * 64 + d0;
      const float4 a = *(const float4*)ks;
      const float4 b = *(const float4*)(ks + 4);
      float xs[8] = {a.x, a.y, a.z, a.w, b.x, b.y, b.z, b.w};
      float s = 0.f;
#pragma unroll
      for (int i = 0; i < 8; ++i) s = fmaf(xs[i], xs[i], s);
      s += __shfl_xor(s, 1); s += __shfl_xor(s, 2); s += __shfl_xor(s, 4);
      if ((t & 7) == 0) diag[n] = s * kDiagCoef;
      short8v h8, l8;
#pragma unroll
      for (int i = 0; i < 8; ++i) { short hh, ll; splitbf(kNorm * xs[i], hh, ll); h8[i] = hh; l8[i] = ll; }
      const int c = sw8(n, d0);
      *(short8v*)&Kh[n][c] = h8;
      *(short8v*)&Kl[n][c] = l8;
      const float* vs = V + headBase + (size_t)(sub * 64 + n) * 64 + d0;
      *(float4*)&vtmp[n][d0] = *(const float4*)vs;
      *(float4*)&vtmp[n][d0 + 4] = *(const float4*)(vs + 4);
    }
    __syncthreads();
    {  // transpose V (+vsum)
      const int e = t & 63, n0 = (t >> 6) * 8;
      short8v h8, l8;
#pragma unroll
      for (int i = 0; i < 8; ++i) {
        float xv = vtmp[n0 + i][e];
        vsum_r += xv;
        short hh, ll; splitbf(xv, hh, ll);
        h8[i] = hh; l8[i] = ll;
      }
      const int c = sw8(e, n0);
      *(short8v*)&Vh[e][c] = h8;
      *(short8v*)&Vl[e][c] = l8;
    }
    __syncthreads();

    float dg4[4];
#pragma unroll
    for (int j = 0; j < 4; ++j) dg4[j] = diag[rt * 16 + (l >> 4) * 4 + j];

    const int arow = rt * 16 + (l & 15);
    short8v ah[2], al[2];
#pragma unroll
    for (int kb = 0; kb < 2; ++kb) {
      const int c = sw8(arow, kb * 32 + koff);
      ah[kb] = *(const short8v*)&Kh[arow][c];
      al[kb] = *(const short8v*)&Kl[arow][c];
    }

    for (int mh = 0; mh < 2; ++mh) {
      // dd GEMM for this wave's 4 m-tiles of the half, then exp -> Et
#pragma unroll
      for (int mt = 0; mt < 4; ++mt) {
        const int mloc = (msel * 4 + mt) * 16 + (l & 15);
        const int mrow = mh * 128 + mloc;
        f32x4 acc = f32x4{0.f, 0.f, 0.f, 0.f};
#pragma unroll
        for (int kb = 0; kb < 2; ++kb) {
          const int c = sw8(mrow, kb * 32 + koff);
          short8v pbh = *(const short8v*)&Ph[mrow][c];
          short8v pbl = *(const short8v*)&Pl[mrow][c];
          acc = MFMA16(ah[kb], pbh, acc);
          acc = MFMA16(ah[kb], pbl, acc);
          acc = MFMA16(al[kb], pbh, acc);
        }
        short4v h4, l4;
        float est = 0.f;
#pragma unroll
        for (int j = 0; j < 4; ++j) {
          float dd = acc[j];
          mx = fmaxf(mx, dd);
          float E = __expf(dd - dg4[j]);
          est += E;
          short hh, ll; splitbf(E, hh, ll);
          h4[j] = hh; l4[j] = ll;
        }
        es[mh][mt] += est;
        const int nbase = rt * 16 + (l >> 4) * 4;
        const int c = sw8(mloc, nbase);
        *(short4v*)&Eh[mloc][c] = h4;
        *(short4v*)&El[mloc][c] = l4;
      }
      __syncthreads();
      {  // ctx GEMM: wave owns Eh rows w*16..+16 (m), all 4 e-tiles
        const int erow = w * 16 + (l & 15);
        short8v eh2[2], el2[2];
#pragma unroll
        for (int kb = 0; kb < 2; ++kb) {
          const int c = sw8(erow, kb * 32 + koff);
          eh2[kb] = *(const short8v*)&Eh[erow][c];
          el2[kb] = *(const short8v*)&El[erow][c];
        }
#pragma unroll
        for (int et = 0; et < 4; ++et) {
          const int ecol = et * 16 + (l & 15);
          f32x4 a2 = cacc[mh][et];
#pragma unroll
          for (int kb = 0; kb < 2; ++kb) {
            const int c = sw8(ecol, kb * 32 + koff);
            short8v vh2 = *(const short8v*)&Vh[ecol][c];
            short8v vl2 = *(const short8v*)&Vl[ecol][c];
            a2 = MFMA16(eh2[kb], vh2, a2);
            a2 = MFMA16(eh2[kb], vl2, a2);
            a2 = MFMA16(el2[kb], vh2, a2);
          }
          cacc[mh][et] = a2;
        }
      }
      __syncthreads();
    }
  }

  // reductions
#pragma unroll
  for (int off = 32; off; off >>= 1) mx = fmaxf(mx, __shfl_xor(mx, off));
  if (l == 0) wpmax[w] = mx;
#pragma unroll
  for (int mh = 0; mh < 2; ++mh)
#pragma unroll
    for (int mt = 0; mt < 4; ++mt) {
      float v2 = es[mh][mt];
      v2 += __shfl_xor(v2, 16);
      v2 += __shfl_xor(v2, 32);
      if (l < 16) atomicAdd(&EsumG[bh * 256 + mh * 128 + (msel * 4 + mt) * 16 + l], v2);
    }
  rpartV[w][l] = vsum_r;
  __syncthreads();
  if (t < 64) {
    float s2 = 0.f;
#pragma unroll
    for (int w2 = 0; w2 < 8; ++w2) s2 += rpartV[w2][t];
    atomicAdd(&VsumG[bh * 64 + t], s2);
  }
  if (t == 0) {
    float b = wpmax[0];
#pragma unroll
    for (int w2 = 1; w2 < 8; ++w2) b = fmaxf(b, wpmax[w2]);
    atomicMax(stabKey + bh, floatKey(b));
  }
#pragma unroll
  for (int mh = 0; mh < 2; ++mh)
#pragma unroll
    for (int et = 0; et < 4; ++et)
#pragma unroll
      for (int j = 0; j < 4; ++j) {
        const int m2 = mh * 128 + w * 16 + (l >> 4) * 4 + j;
        const int e2 = et * 16 + (l & 15);
        atomicAdd(&ctxEG[((size_t)bh * 256 + m2) * 64 + e2], cacc[mh][et][j]);
      }
}

// ---------------------------------------------------------------------------
// Kernel A2: combine. grid 96, block 256.
// ctxhat[m][e] = e^{-stab}*ctxE + eps*Vsum[e] -> transposed bf16 hi/lo [e][m];
// kshat[m] = e^{-stab}*Esum + eps*4096.
// ---------------------------------------------------------------------------
__global__ __launch_bounds__(256) void perf_combine(
    const unsigned* __restrict__ stabKey, const float* __restrict__ EsumG,
    const float* __restrict__ VsumG, const float* __restrict__ ctxEG,
    float* __restrict__ kshatG, short* __restrict__ ctHG, short* __restrict__ ctLG) {
  const int bh = blockIdx.x, t = threadIdx.x;
  const float esc = __expf(-keyToFloat(stabKey[bh]));
  kshatG[bh * 256 + t] = esc * EsumG[bh * 256 + t] + kEps * 4096.0f;
  for (int e = 0; e < 64; ++e) {
    const float v2 = esc * ctxEG[((size_t)bh * 256 + t) * 64 + e] + kEps * VsumG[bh * 64 + e];
    short hh, ll; splitbf(v2, hh, ll);
    ctHG[((size_t)bh * 64 + e) * 256 + t] = hh;
    ctLG[((size_t)bh * 64 + e) * 256 + t] = ll;
  }
}

// ---------------------------------------------------------------------------
// Kernel B: Q-side. grid (96, 64), block 512. 64 q-rows/block.
// dd = (norm*q)·proj^T (split MFMA), rowmax, q' = exp(dd-diag-rowmax)+eps,
// den = q'·kshat, out = (q'·ctxhat)/den via split MFMA.
// ---------------------------------------------------------------------------
__global__ __launch_bounds__(512, 1) void perf_qside(
    const float* __restrict__ Q, const float* __restrict__ proj,
    const float* __restrict__ kshatG, const short* __restrict__ ctHG,
    const short* __restrict__ ctLG, float* __restrict__ out) {
  const int t = threadIdx.x, bh = blockIdx.x, rb = blockIdx.y;
  const int w = t >> 6, l = t & 63;

  __shared__ short Qh[64][64], Ql[64][64];
  __shared__ short Ph[256][64], Pl[256][64];   // reused as ctT halves [64][128]
  __shared__ short qph[64][256], qpl[64][256];
  __shared__ float kshatL[256];
  __shared__ float diagq[64];
  __shared__ unsigned rmaxKey[64];
  __shared__ float denL[64];

  if (t < 64) { rmaxKey[t] = 0u; denL[t] = 0.f; }
  if (t < 256) kshatL[t] = kshatG[bh * 256 + t];

  {  // stage Q (fold norm) + diagq
    const int n = t >> 3, d0 = (t & 7) * 8;
    const float* qs = Q + ((size_t)bh * Nn + rb * 64 + n) * 64 + d0;
    const float4 a = *(const float4*)qs;
    const float4 b = *(const float4*)(qs + 4);
    float xs[8] = {a.x, a.y, a.z, a.w, b.x, b.y, b.z, b.w};
    float s = 0.f;
#pragma unroll
    for (int i = 0; i < 8; ++i) s = fmaf(xs[i], xs[i], s);
    s += __shfl_xor(s, 1); s += __shfl_xor(s, 2); s += __shfl_xor(s, 4);
    if ((t & 7) == 0) diagq[n] = s * kDiagCoef;
    short8v h8, l8;
#pragma unroll
    for (int i = 0; i < 8; ++i) { short hh, ll; splitbf(kNorm * xs[i], hh, ll); h8[i] = hh; l8[i] = ll; }
    const int c = sw8(n, d0);
    *(short8v*)&Qh[n][c] = h8;
    *(short8v*)&Ql[n][c] = l8;
  }
  {  // stage proj
    const int m = t >> 1, d0 = (t & 1) * 32;
    const float* src = proj + m * 64 + d0;
#pragma unroll
    for (int i = 0; i < 4; ++i) {
      float4 a = *(const float4*)(src + i * 8);
      float4 b = *(const float4*)(src + i * 8 + 4);
      float xs[8] = {a.x, a.y, a.z, a.w, b.x, b.y, b.z, b.w};
      short8v h8, l8;
#pragma unroll
      for (int j = 0; j < 8; ++j) { short hh, ll; splitbf(xs[j], hh, ll); h8[j] = hh; l8[j] = ll; }
      const int c = sw8(m, d0 + i * 8);
      *(short8v*)&Ph[m][c] = h8;
      *(short8v*)&Pl[m][c] = l8;
    }
  }
  __syncthreads();

  const int rt = w & 3, msel = w >> 2;
  const int koff = (l >> 4) * 8;
  const int arow = rt * 16 + (l & 15);

  // dd GEMM: wave owns rows rt*16..+16, m-half msel (8 m-tiles)
  f32x4 dacc[8];
  {
    short8v ah[2], al[2];
#pragma unroll
    for (int kb = 0; kb < 2; ++kb) {
      const int c = sw8(arow, kb * 32 + koff);
      ah[kb] = *(const short8v*)&Qh[arow][c];
      al[kb] = *(const short8v*)&Ql[arow][c];
    }
#pragma unroll
    for (int mt = 0; mt < 8; ++mt) {
      const int mrow = msel * 128 + mt * 16 + (l & 15);
      f32x4 acc = f32x4{0.f, 0.f, 0.f, 0.f};
#pragma unroll
      for (int kb = 0; kb < 2; ++kb) {
        const int c = sw8(mrow, kb * 32 + koff);
        short8v pbh = *(const short8v*)&Ph[mrow][c];
        short8v pbl = *(const short8v*)&Pl[mrow][c];
        acc = MFMA16(ah[kb], pbh, acc);
        acc = MFMA16(ah[kb], pbl, acc);
        acc = MFMA16(al[kb], pbh, acc);
      }
      dacc[mt] = acc;
    }
  }
  // rowmax (this wave's half), combine across wave pairs via LDS atomicMax
  {
    float rm[4];
#pragma unroll
    for (int j = 0; j < 4; ++j) {
      float m0 = dacc[0][j];
#pragma unroll
      for (int mt = 1; mt < 8; ++mt) m0 = fmaxf(m0, dacc[mt][j]);
      m0 = fmaxf(m0, __shfl_xor(m0, 1));
      m0 = fmaxf(m0, __shfl_xor(m0, 2));
      m0 = fmaxf(m0, __shfl_xor(m0, 4));
      m0 = fmaxf(m0, __shfl_xor(m0, 8));
      rm[j] = m0;
    }
    if ((l & 15) == 0) {
#pragma unroll
      for (int j = 0; j < 4; ++j)
        atomicMax(&rmaxKey[rt * 16 + (l >> 4) * 4 + j], floatKey(rm[j]));
    }
  }
  __syncthreads();
  // exp -> q' (hi/lo into qp LDS), den partial
  {
    float dg4[4], rx4[4], den4[4];
#pragma unroll
    for (int j = 0; j < 4; ++j) {
      const int r = rt * 16 + (l >> 4) * 4 + j;
      dg4[j] = diagq[r];
      rx4[j] = keyToFloat(rmaxKey[r]);
      den4[j] = 0.f;
    }
#pragma unroll
    for (int mt = 0; mt < 8; ++mt) {
      const int m2 = msel * 128 + mt * 16 + (l & 15);
      const float ks2 = kshatL[m2];
#pragma unroll
      for (int j = 0; j < 4; ++j) {
        const int r = rt * 16 + (l >> 4) * 4 + j;
        float qv = __expf(dacc[mt][j] - dg4[j] - rx4[j]) + kEps;
        den4[j] = fmaf(qv, ks2, den4[j]);
        short hh, ll; splitbf(qv, hh, ll);
        const int c = sw32(r, m2);
        qph[r][c] = hh;
        qpl[r][c] = ll;
      }
    }
#pragma unroll
    for (int j = 0; j < 4; ++j) {
      float d2 = den4[j];
      d2 += __shfl_xor(d2, 1); d2 += __shfl_xor(d2, 2);
      d2 += __shfl_xor(d2, 4); d2 += __shfl_xor(d2, 8);
      if ((l & 15) == 0) atomicAdd(&denL[rt * 16 + (l >> 4) * 4 + j], d2);
    }
  }

  // output GEMM: wave owns rows rt, e-tiles esel*2..+2; K=256 staged in halves
  f32x4 oacc[2] = {f32x4{0.f, 0.f, 0.f, 0.f}, f32x4{0.f, 0.f, 0.f, 0.f}};
  short(*ctTh)[128] = (short(*)[128])Ph;
  short(*ctTl)[128] = (short(*)[128])Pl;
  for (int mh2 = 0; mh2 < 2; ++mh2) {
    __syncthreads();  // prev-half MFMA done / qp+P consumers done
    {  // stage ctxhatT half
      const int e = t >> 3, mg = t & 7;
      const short* gh = ctHG + ((size_t)bh * 64 + e) * 256 + mh2 * 128 + mg * 16;
      const short* gl = ctLG + ((size_t)bh * 64 + e) * 256 + mh2 * 128 + mg * 16;
      short8v a0 = *(const short8v*)gh;
      short8v a1 = *(const short8v*)(gh + 8);
      short8v b0 = *(const short8v*)gl;
      short8v b1 = *(const short8v*)(gl + 8);
      *(short8v*)&ctTh[e][sw16(e, mg * 16)] = a0;
      *(short8v*)&ctTh[e][sw16(e, mg * 16 + 8)] = a1;
      *(short8v*)&ctTl[e][sw16(e, mg * 16)] = b0;
      *(short8v*)&ctTl[e][sw16(e, mg * 16 + 8)] = b1;
    }
    __syncthreads();
#pragma unroll
    for (int kb = 0; kb < 4; ++kb) {
      const int ca = sw32(arow, mh2 * 128 + kb * 32 + koff);
      short8v qh8 = *(const short8v*)&qph[arow][ca];
      short8v ql8 = *(const short8v*)&qpl[arow][ca];
#pragma unroll
      for (int et = 0; et < 2; ++et) {
        const int erow = (msel * 2 + et) * 16 + (l & 15);
        const int cb = sw16(erow, kb * 32 + koff);
        short8v th = *(const short8v*)&ctTh[erow][cb];
        short8v tl = *(const short8v*)&ctTl[erow][cb];
        oacc[et] = MFMA16(qh8, th, oacc[et]);
        oacc[et] = MFMA16(qh8, tl, oacc[et]);
        oacc[et] = MFMA16(ql8, th, oacc[et]);
      }
    }
  }
  // epilogue
  float inv4[4];
#pragma unroll
  for (int j = 0; j < 4; ++j) inv4[j] = 1.0f / denL[rt * 16 + (l >> 4) * 4 + j];
#pragma unroll
  for (int et = 0; et < 2; ++et)
#pragma unroll
    for (int j = 0; j < 4; ++j) {
      const int r = rt * 16 + (l >> 4) * 4 + j;
      const int e2 = (msel * 2 + et) * 16 + (l & 15);
      out[((size_t)bh * Nn + rb * 64 + r) * 64 + e2] = oacc[et][j] * inv4[j];
    }
}

extern "C" void kernel_launch(void* const* d_in, const int* in_sizes, int n_in,
                              void* d_out, int out_size, void* d_ws, size_t ws_size,
                              hipStream_t stream) {
  const float* q = (const float*)d_in[0];
  const float* k = (const float*)d_in[1];
  const float* v = (const float*)d_in[2];
  const float* proj = (const float*)d_in[3];
  float* outp = (float*)d_out;

  char* ws = (char*)d_ws;
  unsigned* stabKey = (unsigned*)(ws + oStab);
  float* EsumG = (float*)(ws + oEsum);
  float* VsumG = (float*)(ws + oVsum);
  float* kshatG = (float*)(ws + oKshat);
  float* ctxEG = (float*)(ws + oCtxE);
  short* ctHG = (short*)(ws + oCtH);
  short* ctLG = (short*)(ws + oCtL);

  hipMemsetAsync(d_ws, 0, kZeroBytes, stream);
  perf_kside<<<dim3(BHn, 16), 512, 0, stream>>>(k, v, proj, stabKey, EsumG, VsumG, ctxEG);
  perf_combine<<<BHn, 256, 0, stream>>>(stabKey, EsumG, VsumG, ctxEG, kshatG, ctHG, ctLG);
  perf_qside<<<dim3(BHn, 64), 512, 0, stream>>>(q, proj, kshatG, ctHG, ctLG, outp);
}